// Round 2
// baseline (787.303 us; speedup 1.0000x reference)
//
#include <hip/hip_runtime.h>
#include <math.h>

#define N_NODES 50000
#define E1N 400000
#define E2N 100000
#define E_TOT 500000
#define ALPHAC 0.2f
#define DAMP 0.85f
#define EPSC 1e-12f

typedef __bf16 bf16_t;
typedef __bf16 bf16x4 __attribute__((ext_vector_type(4)));
typedef __bf16 bf16x8 __attribute__((ext_vector_type(8)));
typedef _Float16 f16_t;
typedef _Float16 f16x4 __attribute__((ext_vector_type(4)));
typedef float f32x16 __attribute__((ext_vector_type(16)));

__device__ __forceinline__ float lrelu(float x) { return x > 0.f ? x : ALPHAC * x; }

// Pack [a1|a2] (K=128, N=256) into 32x32x16 B-fragment order for k_uv.
__global__ __launch_bounds__(256) void k_pack12(const float* __restrict__ a,
                                                bf16_t* __restrict__ bp) {
  int i = blockIdx.x * 256 + threadIdx.x;  // 32768
  if (i >= 32768) return;
  int j = i & 7;
  int l = (i >> 3) & 63;
  int nt = (i >> 9) & 7;
  int ks = i >> 12;
  int c = nt * 32 + (l & 31);
  int o = (c < 128) ? c : c - 128;
  int koff = (c < 128) ? 0 : 128;
  int k = ks * 16 + ((l >> 5) << 3) + j;
  bp[i] = (bf16_t)a[o * 384 + koff + k];
}

// Pack a3 (K=128, N=128) B-fragments for the emb MFMA.
__global__ __launch_bounds__(256) void k_pack3(const float* __restrict__ a,
                                               bf16_t* __restrict__ bp) {
  int i = blockIdx.x * 256 + threadIdx.x;  // 16384
  if (i >= 16384) return;
  int j = i & 7;
  int l = (i >> 3) & 63;
  int nt = (i >> 9) & 3;
  int ks = i >> 11;
  int o = nt * 32 + (l & 31);
  int k = ks * 16 + ((l >> 5) << 3) + j;
  bp[i] = (bf16_t)a[o * 384 + 256 + k];
}

// Edge index split + fused dst-degree count (cnt pre-zeroed).
__global__ __launch_bounds__(256) void k_edges(const int* __restrict__ edge,
                                               const int* __restrict__ nhop,
                                               int* __restrict__ sidx,
                                               int* __restrict__ didx, int stride,
                                               int* __restrict__ cnt) {
  int e = blockIdx.x * 256 + threadIdx.x;
  if (e >= E_TOT) return;
  int s, d;
  if (e < E1N) {
    s = edge[(size_t)e * stride];
    d = edge[(size_t)(E1N + e) * stride];
  } else {
    int t = e - E1N;
    s = nhop[(size_t)t * stride];
    d = nhop[(size_t)(E2N + t) * stride];
  }
  sidx[e] = s;
  didx[e] = d;
  if (cnt) atomicAdd(&cnt[d], 1);
}

// Single-block exclusive scan of cnt[50000] -> csr_start, cursor.
__global__ __launch_bounds__(256) void k_scan(const int* __restrict__ cnt,
                                              int* __restrict__ csr_start,
                                              int* __restrict__ cursor) {
  __shared__ int ls[256];
  __shared__ int lofs[256];
  int t = threadIdx.x;
  int lo = t * 196, hi = lo + 196;
  if (hi > N_NODES) hi = N_NODES;
  int s = 0;
  for (int i = lo; i < hi; ++i) s += cnt[i];
  ls[t] = s;
  __syncthreads();
  if (t == 0) {
    int run = 0;
    for (int i = 0; i < 256; ++i) { lofs[i] = run; run += ls[i]; }
  }
  __syncthreads();
  int run = lofs[t];
  for (int i = lo; i < hi; ++i) {
    csr_start[i] = run;
    cursor[i] = run;
    run += cnt[i];
  }
}

// Scatter edge ids into dst-sorted order (order within segment irrelevant).
__global__ __launch_bounds__(256) void k_pos(const int* __restrict__ didx,
                                             int* __restrict__ cursor,
                                             int* __restrict__ eid) {
  int e = blockIdx.x * 256 + threadIdx.x;
  if (e >= E_TOT) return;
  int pos = atomicAdd(&cursor[didx[e]], 1);
  eid[pos] = e;
}

// UV = input @ [a1|a2].T -> bf16 [N_NODES][256].
__global__ __launch_bounds__(256) void k_uv(const float* __restrict__ input,
                                            const bf16_t* __restrict__ bp12,
                                            bf16_t* __restrict__ uv) {
  const int tid = threadIdx.x, lane = tid & 63, wv = tid >> 6;
  const int n0 = blockIdx.x * 128 + wv * 32;
  const int m = lane & 31, hi2 = lane >> 5;
  int n = n0 + m;
  if (n >= N_NODES) n = 0;
  const float* ar = input + (size_t)n * 128 + hi2 * 8;
  const bf16x8* bp = (const bf16x8*)bp12;

  f32x16 acc[8];
#pragma unroll
  for (int nt = 0; nt < 8; ++nt)
#pragma unroll
    for (int r = 0; r < 16; ++r) acc[nt][r] = 0.f;

#pragma unroll
  for (int ks = 0; ks < 8; ++ks) {
    float4 u0 = *(const float4*)(ar + ks * 16);
    float4 u1 = *(const float4*)(ar + ks * 16 + 4);
    bf16x8 af = {(bf16_t)u0.x, (bf16_t)u0.y, (bf16_t)u0.z, (bf16_t)u0.w,
                 (bf16_t)u1.x, (bf16_t)u1.y, (bf16_t)u1.z, (bf16_t)u1.w};
#pragma unroll
    for (int nt = 0; nt < 8; ++nt)
      acc[nt] = __builtin_amdgcn_mfma_f32_32x32x16_bf16(af, bp[(ks * 8 + nt) * 64 + lane],
                                                        acc[nt], 0, 0, 0);
  }
#pragma unroll
  for (int nt = 0; nt < 8; ++nt)
#pragma unroll
    for (int r = 0; r < 16; ++r) {
      int row = (r & 3) + ((r >> 2) << 3) + (hi2 << 2);
      int node = n0 + row;
      if (node < N_NODES) uv[(size_t)node * 256 + nt * 32 + m] = (bf16_t)acc[nt][r];
    }
}

// Fused pass: coalesced LDS-staged emb GEMM (from k_gemm3) + C bounced to fp16
// in the SAME 32KB LDS + per-edge epilogue: P = lrelu(C + U[src] + V[dst])
// written row-major bf16 to global, fused a2-dot -> edge_e + a_rowsum atomic.
__global__ __launch_bounds__(256, 4) void k_passA2(
    const float* __restrict__ eemb, const float* __restrict__ eembn,
    const bf16_t* __restrict__ uv, const int* __restrict__ sidx,
    const int* __restrict__ didx, const bf16_t* __restrict__ bp3,
    const float* __restrict__ a2, float* __restrict__ edge_e,
    float* __restrict__ a_rowsum, bf16_t* __restrict__ P) {
  __shared__ __align__(16) char s_raw[32768];  // 128 rows x 256B, swizzled
  const int tid = threadIdx.x;
  const long long e0 = (long long)blockIdx.x * 128;

  // Phase 1: stage A tile (128 rows x 128 f32 -> bf16 LDS), 8-deep load batches.
  {
    const int r8 = tid >> 5;          // 0..7
    const int cb = (tid & 31) * 8;    // byte col of a bf16x4 (4 floats)
#pragma unroll
    for (int c = 0; c < 2; ++c) {
      float4 rg[8];
#pragma unroll
      for (int i = 0; i < 8; ++i) {
        int row = (c * 8 + i) * 8 + r8;
        long long e = e0 + row;
        rg[i] = make_float4(0.f, 0.f, 0.f, 0.f);
        if (e < E_TOT) {
          const float* src = (e < E1N) ? eemb + (size_t)e * 128
                                       : eembn + (size_t)(e - E1N) * 128;
          rg[i] = *(const float4*)(src + (cb >> 1));
        }
      }
#pragma unroll
      for (int i = 0; i < 8; ++i) {
        int row = (c * 8 + i) * 8 + r8;
        bf16x4 b = {(bf16_t)rg[i].x, (bf16_t)rg[i].y, (bf16_t)rg[i].z, (bf16_t)rg[i].w};
        *(bf16x4*)(s_raw + row * 256 + (cb ^ ((row & 7) << 4))) = b;
      }
    }
  }
  __syncthreads();

  // Phase 2: GEMM emb @ a3^T from LDS.
  const int lane = tid & 63, wv = tid >> 6;
  const int m = lane & 31, hi2 = lane >> 5;
  const int arow = wv * 32 + m;
  const int swz = (arow & 7) << 4;
  const bf16x8* bp = (const bf16x8*)bp3;

  f32x16 acc[4];
#pragma unroll
  for (int nt = 0; nt < 4; ++nt)
#pragma unroll
    for (int r = 0; r < 16; ++r) acc[nt][r] = 0.f;

  bf16x8 bb[4], bn[4];
#pragma unroll
  for (int nt = 0; nt < 4; ++nt) bb[nt] = bp[nt * 64 + lane];

#pragma unroll
  for (int ks = 0; ks < 8; ++ks) {
    bf16x8 af = *(const bf16x8*)(s_raw + arow * 256 + ((ks * 32 + hi2 * 16) ^ swz));
    if (ks < 7) {
#pragma unroll
      for (int nt = 0; nt < 4; ++nt) bn[nt] = bp[((ks + 1) * 4 + nt) * 64 + lane];
    }
#pragma unroll
    for (int nt = 0; nt < 4; ++nt)
      acc[nt] = __builtin_amdgcn_mfma_f32_32x32x16_bf16(af, bb[nt], acc[nt], 0, 0, 0);
#pragma unroll
    for (int nt = 0; nt < 4; ++nt) bb[nt] = bn[nt];
  }
  __syncthreads();

  // Phase 3: C bounce as fp16 into the same LDS (each wave owns rows wv*32..+31).
#pragma unroll
  for (int nt = 0; nt < 4; ++nt)
#pragma unroll
    for (int r = 0; r < 16; ++r) {
      int orow = (r & 3) + ((r >> 2) << 3) + (hi2 << 2);
      int row = wv * 32 + orow;
      int cb = (nt * 32 + m) * 2;
      *(f16_t*)(s_raw + row * 256 + (cb ^ ((row & 7) << 4))) = (f16_t)acc[nt][r];
    }
  __syncthreads();

  // Phase 4: per-edge epilogue. One 32-lane group per edge row; coalesced
  // u/v gather (256B), P row-major store, fused a2-dot + edge_e + a_rowsum.
  {
    const int g = tid >> 5;           // 0..7
    const int ml = tid & 31;
    const int cl = ml * 4;            // 4 cols per lane
    const float4 a2v = *(const float4*)(a2 + cl);
#pragma unroll
    for (int i = 0; i < 16; ++i) {
      int row = i * 8 + g;
      long long e = e0 + row;
      if (e >= E_TOT) break;  // uniform within the 32-lane group
      int s = sidx[e], d = didx[e];
      bf16x4 uu = *(const bf16x4*)(uv + (size_t)s * 256 + cl);
      bf16x4 vv = *(const bf16x4*)(uv + (size_t)d * 256 + 128 + cl);
      f16x4 cc = *(const f16x4*)(s_raw + row * 256 + ((cl * 2) ^ ((row & 7) << 4)));
      float p0 = lrelu((float)cc[0] + (float)uu[0] + (float)vv[0]);
      float p1 = lrelu((float)cc[1] + (float)uu[1] + (float)vv[1]);
      float p2 = lrelu((float)cc[2] + (float)uu[2] + (float)vv[2]);
      float p3 = lrelu((float)cc[3] + (float)uu[3] + (float)vv[3]);
      bf16x4 po = {(bf16_t)p0, (bf16_t)p1, (bf16_t)p2, (bf16_t)p3};
      *(bf16x4*)(P + (size_t)e * 128 + cl) = po;
      float sac = p0 * a2v.x + p1 * a2v.y + p2 * a2v.z + p3 * a2v.w;
#pragma unroll
      for (int off = 1; off < 32; off <<= 1) sac += __shfl_xor(sac, off, 64);
      if (ml == 0) {
        float ev = expf(-lrelu(sac));
        edge_e[e] = ev;
        atomicAdd(&a_rowsum[d], ev);
      }
    }
  }
}

// h_prime: one 32-lane group per dst node; coalesced 256B row-major P reads,
// w = rel_att * new_rank[src] computed inline, elu fused, float4 writes.
__global__ __launch_bounds__(256) void k_hprime(const bf16_t* __restrict__ P,
                                                const int* __restrict__ eid,
                                                const int* __restrict__ csr_start,
                                                const int* __restrict__ cnt,
                                                const float* __restrict__ rel_att,
                                                const int* __restrict__ sidx,
                                                const float* __restrict__ new_rank,
                                                float* __restrict__ out) {
  int g = (blockIdx.x << 3) | (threadIdx.x >> 5);
  if (g >= N_NODES) return;
  int m = threadIdx.x & 31;
  int start = csr_start[g], deg = cnt[g];
  float a0 = 0.f, a1 = 0.f, a2v = 0.f, a3v = 0.f;
  for (int i = 0; i < deg; ++i) {
    int e = eid[start + i];
    float we = rel_att[e] * new_rank[sidx[e]];
    bf16x4 p = *(const bf16x4*)(P + (size_t)e * 128 + m * 4);
    a0 += we * (float)p[0];
    a1 += we * (float)p[1];
    a2v += we * (float)p[2];
    a3v += we * (float)p[3];
  }
  float4 r;
  r.x = a0 > 0.f ? a0 : expm1f(a0);
  r.y = a1 > 0.f ? a1 : expm1f(a1);
  r.z = a2v > 0.f ? a2v : expm1f(a2v);
  r.w = a3v > 0.f ? a3v : expm1f(a3v);
  *(float4*)(out + (size_t)g * 128 + m * 4) = r;
}

// ---------- fallback (round-3) recompute-ACCUM pass ----------
template <bool ACCUM>
__global__ __launch_bounds__(256, 3) void k_pass(
    const float* __restrict__ eemb, const float* __restrict__ eembn,
    const bf16_t* __restrict__ uv, const int* __restrict__ sidx,
    const int* __restrict__ didx, const bf16_t* __restrict__ bp3,
    const float* __restrict__ a2, float* __restrict__ edge_e,
    float* __restrict__ a_rowsum, const float* __restrict__ rel_att,
    const float* __restrict__ new_rank, float* __restrict__ hout) {
  __shared__ bf16_t s_sum[128][136];
  const int tid = threadIdx.x;
  const long long e0 = (long long)blockIdx.x * 128;
  {
    const int g = tid >> 5;
    const int cl = (tid & 31) * 4;
#pragma unroll
    for (int i = 0; i < 16; ++i) {
      int el = i * 8 + g;
      long long e = e0 + el;
      float sx = 0.f, sy = 0.f, sz = 0.f, sw = 0.f;
      if (e < E_TOT) {
        int s = sidx[e], d = didx[e];
        bf16x4 u = *(const bf16x4*)(uv + (size_t)s * 256 + cl);
        bf16x4 v = *(const bf16x4*)(uv + (size_t)d * 256 + 128 + cl);
        sx = (float)u[0] + (float)v[0];
        sy = (float)u[1] + (float)v[1];
        sz = (float)u[2] + (float)v[2];
        sw = (float)u[3] + (float)v[3];
      }
      bf16x4 o = {(bf16_t)sx, (bf16_t)sy, (bf16_t)sz, (bf16_t)sw};
      *(bf16x4*)&s_sum[el][cl] = o;
    }
  }
  __syncthreads();

  const int lane = tid & 63;
  const int wv = tid >> 6;
  const long long e0w = e0 + wv * 32;
  if (e0w >= E_TOT) return;
  const int m = lane & 31, hi2 = lane >> 5;
  const long long e = e0w + m;
  const float* b2 = (e < E1N) ? (eemb + (size_t)e * 128)
                              : (eembn + (size_t)(e - E1N) * 128);
  const float* ar = b2 + hi2 * 8;

  const bf16x8* bp = (const bf16x8*)bp3;
  f32x16 acc[4];
#pragma unroll
  for (int nt = 0; nt < 4; ++nt)
#pragma unroll
    for (int r = 0; r < 16; ++r) acc[nt][r] = 0.f;

  auto loadA = [&](int ks) -> bf16x8 {
    float4 u0 = *(const float4*)(ar + ks * 16);
    float4 u1 = *(const float4*)(ar + ks * 16 + 4);
    bf16x8 rr = {(bf16_t)u0.x, (bf16_t)u0.y, (bf16_t)u0.z, (bf16_t)u0.w,
                 (bf16_t)u1.x, (bf16_t)u1.y, (bf16_t)u1.z, (bf16_t)u1.w};
    return rr;
  };

  bf16x8 a_cur = loadA(0);
  bf16x8 bb[4], bn[4];
#pragma unroll
  for (int nt = 0; nt < 4; ++nt) bb[nt] = bp[nt * 64 + lane];

#pragma unroll
  for (int ks = 0; ks < 8; ++ks) {
    bf16x8 a_nxt;
    if (ks < 7) {
      a_nxt = loadA(ks + 1);
#pragma unroll
      for (int nt = 0; nt < 4; ++nt) bn[nt] = bp[((ks + 1) * 4 + nt) * 64 + lane];
    }
#pragma unroll
    for (int nt = 0; nt < 4; ++nt)
      acc[nt] = __builtin_amdgcn_mfma_f32_32x32x16_bf16(a_cur, bb[nt], acc[nt], 0, 0, 0);
    a_cur = a_nxt;
#pragma unroll
    for (int nt = 0; nt < 4; ++nt) bb[nt] = bn[nt];
  }

  if (!ACCUM) {
    float sac[16];
#pragma unroll
    for (int r = 0; r < 16; ++r) sac[r] = 0.f;
#pragma unroll
    for (int nt = 0; nt < 4; ++nt) {
      float a2v = a2[nt * 32 + m];
      int o = nt * 32 + m;
#pragma unroll
      for (int r = 0; r < 16; ++r) {
        int row = (r & 3) + ((r >> 2) << 3) + (hi2 << 2);
        float c = acc[nt][r] + (float)s_sum[wv * 32 + row][o];
        sac[r] += lrelu(c) * a2v;
      }
    }
#pragma unroll
    for (int off = 1; off < 32; off <<= 1) {
#pragma unroll
      for (int r = 0; r < 16; ++r) sac[r] += __shfl_xor(sac[r], off, 64);
    }
    if (m == 0) {
#pragma unroll
      for (int r = 0; r < 16; ++r) {
        int row = (r & 3) + ((r >> 2) << 3) + (hi2 << 2);
        long long ee_i = e0w + row;
        float ev = expf(-lrelu(sac[r]));
        edge_e[ee_i] = ev;
        atomicAdd(&a_rowsum[didx[ee_i]], ev);
      }
    }
  } else {
    float w_m = rel_att[e] * new_rank[sidx[e]];
    int d = didx[e];
    float wr[16];
    int dr[16];
#pragma unroll
    for (int r = 0; r < 16; ++r) {
      int row = (r & 3) + ((r >> 2) << 3) + (hi2 << 2);
      wr[r] = __shfl(w_m, row, 64);
      dr[r] = __shfl(d, row, 64);
    }
#pragma unroll
    for (int nt = 0; nt < 4; ++nt) {
      int o = nt * 32 + m;
#pragma unroll
      for (int r = 0; r < 16; ++r) {
        int row = (r & 3) + ((r >> 2) << 3) + (hi2 << 2);
        float c = acc[nt][r] + (float)s_sum[wv * 32 + row][o];
        atomicAdd(&hout[(size_t)dr[r] * 128 + o], lrelu(c) * wr[r]);
      }
    }
  }
}

__global__ __launch_bounds__(256) void k_relatt(const float* __restrict__ edge_e,
                                                const int* __restrict__ didx,
                                                const int* __restrict__ sidx,
                                                const float* __restrict__ a_rowsum,
                                                float* __restrict__ rel_att,
                                                float* __restrict__ e_rowsum) {
  int e = blockIdx.x * 256 + threadIdx.x;
  if (e >= E_TOT) return;
  float rs = a_rowsum[didx[e]];
  rs = (rs == 0.f) ? EPSC : rs;
  float r = edge_e[e] / rs;
  rel_att[e] = r;
  atomicAdd(&e_rowsum[sidx[e]], r);
}

__global__ __launch_bounds__(256) void k_val(const float* __restrict__ rel_att,
                                             const int* __restrict__ sidx,
                                             const int* __restrict__ didx,
                                             const float* __restrict__ rank,
                                             const float* __restrict__ e_rowsum,
                                             float* __restrict__ e_colsum) {
  int e = blockIdx.x * 256 + threadIdx.x;
  if (e >= E_TOT) return;
  int s = sidx[e];
  float er = e_rowsum[s];
  er = (er == 0.f) ? EPSC : er;
  float val = rel_att[e] * rank[s] / er;
  atomicAdd(&e_colsum[didx[e]], val);
}

__global__ __launch_bounds__(256) void k_rank(const float* __restrict__ e_colsum,
                                              float* __restrict__ new_rank,
                                              float* __restrict__ out_tail) {
  int n = blockIdx.x * 256 + threadIdx.x;
  if (n >= N_NODES) return;
  float nr = 1.f - DAMP + DAMP * e_colsum[n];
  new_rank[n] = nr;
  out_tail[n] = nr;
}

__global__ __launch_bounds__(256) void k_elu(float* __restrict__ h) {
  int i = blockIdx.x * 256 + threadIdx.x;
  if (i < N_NODES * 128) {
    float x = h[i];
    h[i] = x > 0.f ? x : expm1f(x);
  }
}

extern "C" void kernel_launch(void* const* d_in, const int* in_sizes, int n_in,
                              void* d_out, int out_size, void* d_ws, size_t ws_size,
                              hipStream_t stream) {
  const float* input = (const float*)d_in[0];
  const int* edge = (const int*)d_in[1];
  const float* eemb = (const float*)d_in[2];
  const int* enh = (const int*)d_in[3];
  const float* eembn = (const float*)d_in[4];
  const float* rank = (const float*)d_in[5];
  const float* a = (const float*)d_in[6];
  const float* a2 = (const float*)d_in[7];
  float* out = (float*)d_out;

  int estride = (in_sizes[1] == 2 * E1N) ? 1 : 2;

  char* ws = (char*)d_ws;
  bf16_t* bp12 = (bf16_t*)(ws);                 //     65,536
  bf16_t* bp3 = (bf16_t*)(ws + 65536);          //     32,768
  bf16_t* uv = (bf16_t*)(ws + 98304);           // 25,600,000
  int* sidx = (int*)(ws + 25698304);            //  2,000,000
  int* didx = (int*)(ws + 27698304);            //  2,000,000
  float* edge_e = (float*)(ws + 29698304);      //  2,000,000
  float* rel_att = (float*)(ws + 31698304);     //  2,000,000
  // ws + 33698304: 2,000,000 (spare)
  int* eid = (int*)(ws + 35698304);             //  2,000,000
  int* csr_start = (int*)(ws + 37698304);       //    200,000
  int* cursor = (int*)(ws + 37898304);          //    200,000
  int* cnt = (int*)(ws + 38098304);             //    200,000
  float* a_rowsum = (float*)(ws + 38298304);    //    200,000
  float* e_rowsum = (float*)(ws + 38498304);    //    200,000
  float* e_colsum = (float*)(ws + 38698304);    //    200,000
  float* new_rank = (float*)(ws + 38898304);    //    200,000
  bf16_t* P = (bf16_t*)(ws + 39098304);         // 128,000,000 -> 167,098,304

  const bool big = ws_size >= 167098304ULL;

  const int NB = (E_TOT + 127) / 128;
  const int EB = (E_TOT + 255) / 256;

  if (big) {
    // zero cnt + a_rowsum + e_rowsum + e_colsum (contiguous)
    hipMemsetAsync(cnt, 0, 4 * 200000, stream);

    k_pack12<<<128, 256, 0, stream>>>(a, bp12);
    k_pack3<<<64, 256, 0, stream>>>(a, bp3);
    k_edges<<<EB, 256, 0, stream>>>(edge, enh, sidx, didx, estride, cnt);
    k_scan<<<1, 256, 0, stream>>>(cnt, csr_start, cursor);
    k_pos<<<EB, 256, 0, stream>>>(didx, cursor, eid);
    k_uv<<<(N_NODES + 127) / 128, 256, 0, stream>>>(input, bp12, uv);

    k_passA2<<<NB, 256, 0, stream>>>(eemb, eembn, uv, sidx, didx, bp3, a2,
                                     edge_e, a_rowsum, P);
    k_relatt<<<EB, 256, 0, stream>>>(edge_e, didx, sidx, a_rowsum, rel_att, e_rowsum);
    k_val<<<EB, 256, 0, stream>>>(rel_att, sidx, didx, rank, e_rowsum, e_colsum);
    k_rank<<<(N_NODES + 255) / 256, 256, 0, stream>>>(e_colsum, new_rank,
                                                      out + (size_t)N_NODES * 128);
    k_hprime<<<(N_NODES + 7) / 8, 256, 0, stream>>>(P, eid, csr_start, cnt, rel_att,
                                                    sidx, new_rank, out);
  } else {
    // fallback: two-pass recompute + atomic hout
    hipMemsetAsync(cnt, 0, 4 * 200000, stream);
    hipMemsetAsync(out, 0, (size_t)N_NODES * 128 * 4, stream);

    k_pack12<<<128, 256, 0, stream>>>(a, bp12);
    k_pack3<<<64, 256, 0, stream>>>(a, bp3);
    k_edges<<<EB, 256, 0, stream>>>(edge, enh, sidx, didx, estride, nullptr);
    k_uv<<<(N_NODES + 127) / 128, 256, 0, stream>>>(input, bp12, uv);

    k_pass<false><<<NB, 256, 0, stream>>>(eemb, eembn, uv, sidx, didx, bp3, a2,
                                          edge_e, a_rowsum, nullptr, nullptr, nullptr);
    k_relatt<<<EB, 256, 0, stream>>>(edge_e, didx, sidx, a_rowsum, rel_att, e_rowsum);
    k_val<<<EB, 256, 0, stream>>>(rel_att, sidx, didx, rank, e_rowsum, e_colsum);
    k_rank<<<(N_NODES + 255) / 256, 256, 0, stream>>>(e_colsum, new_rank,
                                                      out + (size_t)N_NODES * 128);
    k_pass<true><<<NB, 256, 0, stream>>>(eemb, eembn, uv, sidx, didx, bp3, a2,
                                         nullptr, nullptr, rel_att, new_rank, out);
    k_elu<<<(N_NODES * 128 + 255) / 256, 256, 0, stream>>>(out);
  }
}

// Round 3
// 743.979 us; speedup vs baseline: 1.0582x; 1.0582x over previous
//
#include <hip/hip_runtime.h>
#include <math.h>

#define N_NODES 50000
#define E1N 400000
#define E2N 100000
#define E_TOT 500000
#define ALPHAC 0.2f
#define DAMP 0.85f
#define EPSC 1e-12f

typedef __bf16 bf16_t;
typedef __bf16 bf16x4 __attribute__((ext_vector_type(4)));
typedef __bf16 bf16x8 __attribute__((ext_vector_type(8)));
typedef _Float16 f16_t;
typedef _Float16 f16x4 __attribute__((ext_vector_type(4)));
typedef float f32x4 __attribute__((ext_vector_type(4)));
typedef float f32x16 __attribute__((ext_vector_type(16)));

__device__ __forceinline__ float lrelu(float x) { return x > 0.f ? x : ALPHAC * x; }

// Pack [a1|a2] (K=128, N=256) into 32x32x16 B-fragment order for k_uv.
__global__ __launch_bounds__(256) void k_pack12(const float* __restrict__ a,
                                                bf16_t* __restrict__ bp) {
  int i = blockIdx.x * 256 + threadIdx.x;  // 32768
  if (i >= 32768) return;
  int j = i & 7;
  int l = (i >> 3) & 63;
  int nt = (i >> 9) & 7;
  int ks = i >> 12;
  int c = nt * 32 + (l & 31);
  int o = (c < 128) ? c : c - 128;
  int koff = (c < 128) ? 0 : 128;
  int k = ks * 16 + ((l >> 5) << 3) + j;
  bp[i] = (bf16_t)a[o * 384 + koff + k];
}

// Pack a3 (K=128, N=128) B-fragments, 32x32x16 order (fallback path).
__global__ __launch_bounds__(256) void k_pack3(const float* __restrict__ a,
                                               bf16_t* __restrict__ bp) {
  int i = blockIdx.x * 256 + threadIdx.x;  // 16384
  if (i >= 16384) return;
  int j = i & 7;
  int l = (i >> 3) & 63;
  int nt = (i >> 9) & 3;
  int ks = i >> 11;
  int o = nt * 32 + (l & 31);
  int k = ks * 16 + ((l >> 5) << 3) + j;
  bp[i] = (bf16_t)a[o * 384 + 256 + k];
}

// Pack a3 (K=128, N=128) B-fragments, 16x16x32 order (passA3).
// B: col = lane&15, k = ks*32 + (lane>>4)*8 + j.
__global__ __launch_bounds__(256) void k_pack3c(const float* __restrict__ a,
                                                bf16_t* __restrict__ bp) {
  int i = blockIdx.x * 256 + threadIdx.x;  // 16384
  if (i >= 16384) return;
  int j = i & 7;
  int l = (i >> 3) & 63;
  int nt = (i >> 9) & 7;
  int ks = i >> 12;
  int o = nt * 16 + (l & 15);
  int k = ks * 32 + ((l >> 4) << 3) + j;
  bp[i] = (bf16_t)a[o * 384 + 256 + k];
}

// Edge index split + fused dst-degree count (cnt pre-zeroed).
__global__ __launch_bounds__(256) void k_edges(const int* __restrict__ edge,
                                               const int* __restrict__ nhop,
                                               int* __restrict__ sidx,
                                               int* __restrict__ didx, int stride,
                                               int* __restrict__ cnt) {
  int e = blockIdx.x * 256 + threadIdx.x;
  if (e >= E_TOT) return;
  int s, d;
  if (e < E1N) {
    s = edge[(size_t)e * stride];
    d = edge[(size_t)(E1N + e) * stride];
  } else {
    int t = e - E1N;
    s = nhop[(size_t)t * stride];
    d = nhop[(size_t)(E2N + t) * stride];
  }
  sidx[e] = s;
  didx[e] = d;
  if (cnt) atomicAdd(&cnt[d], 1);
}

// Single-block exclusive scan of cnt[50000] -> csr_start, cursor.
__global__ __launch_bounds__(256) void k_scan(const int* __restrict__ cnt,
                                              int* __restrict__ csr_start,
                                              int* __restrict__ cursor) {
  __shared__ int ls[256];
  __shared__ int lofs[256];
  int t = threadIdx.x;
  int lo = t * 196, hi = lo + 196;
  if (hi > N_NODES) hi = N_NODES;
  int s = 0;
  for (int i = lo; i < hi; ++i) s += cnt[i];
  ls[t] = s;
  __syncthreads();
  if (t == 0) {
    int run = 0;
    for (int i = 0; i < 256; ++i) { lofs[i] = run; run += ls[i]; }
  }
  __syncthreads();
  int run = lofs[t];
  for (int i = lo; i < hi; ++i) {
    csr_start[i] = run;
    cursor[i] = run;
    run += cnt[i];
  }
}

// Scatter edge ids into dst-sorted order (order within segment irrelevant).
__global__ __launch_bounds__(256) void k_pos(const int* __restrict__ didx,
                                             int* __restrict__ cursor,
                                             int* __restrict__ eid) {
  int e = blockIdx.x * 256 + threadIdx.x;
  if (e >= E_TOT) return;
  int pos = atomicAdd(&cursor[didx[e]], 1);
  eid[pos] = e;
}

// UV = input @ [a1|a2].T -> bf16 [N_NODES][256].
__global__ __launch_bounds__(256) void k_uv(const float* __restrict__ input,
                                            const bf16_t* __restrict__ bp12,
                                            bf16_t* __restrict__ uv) {
  const int tid = threadIdx.x, lane = tid & 63, wv = tid >> 6;
  const int n0 = blockIdx.x * 128 + wv * 32;
  const int m = lane & 31, hi2 = lane >> 5;
  int n = n0 + m;
  if (n >= N_NODES) n = 0;
  const float* ar = input + (size_t)n * 128 + hi2 * 8;
  const bf16x8* bp = (const bf16x8*)bp12;

  f32x16 acc[8];
#pragma unroll
  for (int nt = 0; nt < 8; ++nt)
#pragma unroll
    for (int r = 0; r < 16; ++r) acc[nt][r] = 0.f;

#pragma unroll
  for (int ks = 0; ks < 8; ++ks) {
    float4 u0 = *(const float4*)(ar + ks * 16);
    float4 u1 = *(const float4*)(ar + ks * 16 + 4);
    bf16x8 af = {(bf16_t)u0.x, (bf16_t)u0.y, (bf16_t)u0.z, (bf16_t)u0.w,
                 (bf16_t)u1.x, (bf16_t)u1.y, (bf16_t)u1.z, (bf16_t)u1.w};
#pragma unroll
    for (int nt = 0; nt < 8; ++nt)
      acc[nt] = __builtin_amdgcn_mfma_f32_32x32x16_bf16(af, bp[(ks * 8 + nt) * 64 + lane],
                                                        acc[nt], 0, 0, 0);
  }
#pragma unroll
  for (int nt = 0; nt < 8; ++nt)
#pragma unroll
    for (int r = 0; r < 16; ++r) {
      int row = (r & 3) + ((r >> 2) << 3) + (hi2 << 2);
      int node = n0 + row;
      if (node < N_NODES) uv[(size_t)node * 256 + nt * 32 + m] = (bf16_t)acc[nt][r];
    }
}

// Fused pass, 16x16x32 variant: 64-row tiles, 32 acc VGPR/wave (vs 64 AGPR for
// 32x32) so occupancy can exceed the 4-waves/SIMD unified-register cap.
// Phase 1: coalesced contiguous stage of 64 emb rows (f32->bf16, swizzled LDS).
// Phase 2: GEMM emb @ a3^T; wave w computes rows w*16..+15 x 128 cols.
// Phase 3: C bounced as fp16 into same 16KB LDS.
// Phase 4: per-edge epilogue: P = lrelu(C+U[src]+V[dst]) row-major bf16,
//          fused a2-dot -> edge_e + a_rowsum atomic.
__global__ __launch_bounds__(256) void k_passA3(
    const float* __restrict__ eemb, const float* __restrict__ eembn,
    const bf16_t* __restrict__ uv, const int* __restrict__ sidx,
    const int* __restrict__ didx, const bf16_t* __restrict__ bp3c,
    const float* __restrict__ a2, float* __restrict__ edge_e,
    float* __restrict__ a_rowsum, bf16_t* __restrict__ P) {
  __shared__ __align__(16) char s_raw[16384];  // 64 rows x 256B, swizzled
  const int tid = threadIdx.x;
  const long long e0 = (long long)blockIdx.x * 64;

  // Phase 1: 64 rows x 128 f32, fully coalesced (consecutive edges contiguous).
#pragma unroll
  for (int s = 0; s < 8; ++s) {
    int idx = s * 1024 + tid * 4;  // float index in [0, 8192)
    int row = idx >> 7, col = idx & 127;
    long long e = e0 + row;
    float4 u = make_float4(0.f, 0.f, 0.f, 0.f);
    if (e < E_TOT) {
      const float* src = (e < E1N) ? eemb + (size_t)e * 128
                                   : eembn + (size_t)(e - E1N) * 128;
      u = *(const float4*)(src + col);
    }
    bf16x4 b = {(bf16_t)u.x, (bf16_t)u.y, (bf16_t)u.z, (bf16_t)u.w};
    *(bf16x4*)(s_raw + row * 256 + ((col * 2) ^ ((row & 7) << 4))) = b;
  }
  __syncthreads();

  // Phase 2: GEMM. A-frag: row = lane&15, k = ks*32 + (lane>>4)*8 + j.
  const int lane = tid & 63, wv = tid >> 6;
  const int cc = lane & 15, kg = lane >> 4;
  const int arow = wv * 16 + cc;
  const int swz = (arow & 7) << 4;
  const bf16x8* bpc = (const bf16x8*)bp3c;

  f32x4 acc[8];
#pragma unroll
  for (int nt = 0; nt < 8; ++nt) acc[nt] = (f32x4){0.f, 0.f, 0.f, 0.f};

#pragma unroll
  for (int ks = 0; ks < 4; ++ks) {
    bf16x8 af = *(const bf16x8*)(s_raw + arow * 256 + ((ks * 64 + kg * 16) ^ swz));
#pragma unroll
    for (int nt = 0; nt < 8; ++nt)
      acc[nt] = __builtin_amdgcn_mfma_f32_16x16x32_bf16(
          af, bpc[(ks * 8 + nt) * 64 + lane], acc[nt], 0, 0, 0);
  }
  __syncthreads();

  // Phase 3: C -> fp16 LDS. C layout: col = lane&15, row = (lane>>4)*4 + r.
#pragma unroll
  for (int nt = 0; nt < 8; ++nt)
#pragma unroll
    for (int r = 0; r < 4; ++r) {
      int row = wv * 16 + kg * 4 + r;
      int cb = (nt * 16 + cc) * 2;
      *(f16_t*)(s_raw + row * 256 + (cb ^ ((row & 7) << 4))) = (f16_t)acc[nt][r];
    }
  __syncthreads();

  // Phase 4: per-edge epilogue, one 32-lane group per edge row.
  {
    const int g = tid >> 5;  // 0..7
    const int ml = tid & 31;
    const int cl = ml * 4;
    const float4 a2v = *(const float4*)(a2 + cl);
    int sarr[8], darr[8];
#pragma unroll
    for (int i = 0; i < 8; ++i) {
      long long e = e0 + i * 8 + g;
      sarr[i] = 0;
      darr[i] = 0;
      if (e < E_TOT) {
        sarr[i] = sidx[e];
        darr[i] = didx[e];
      }
    }
#pragma unroll
    for (int i = 0; i < 8; ++i) {
      int row = i * 8 + g;
      long long e = e0 + row;
      if (e >= E_TOT) break;  // uniform within the 32-lane group
      bf16x4 uu = *(const bf16x4*)(uv + (size_t)sarr[i] * 256 + cl);
      bf16x4 vv = *(const bf16x4*)(uv + (size_t)darr[i] * 256 + 128 + cl);
      f16x4 cc4 = *(const f16x4*)(s_raw + row * 256 + ((cl * 2) ^ ((row & 7) << 4)));
      float p0 = lrelu((float)cc4[0] + (float)uu[0] + (float)vv[0]);
      float p1 = lrelu((float)cc4[1] + (float)uu[1] + (float)vv[1]);
      float p2 = lrelu((float)cc4[2] + (float)uu[2] + (float)vv[2]);
      float p3 = lrelu((float)cc4[3] + (float)uu[3] + (float)vv[3]);
      bf16x4 po = {(bf16_t)p0, (bf16_t)p1, (bf16_t)p2, (bf16_t)p3};
      *(bf16x4*)(P + (size_t)e * 128 + cl) = po;
      float sac = p0 * a2v.x + p1 * a2v.y + p2 * a2v.z + p3 * a2v.w;
#pragma unroll
      for (int off = 1; off < 32; off <<= 1) sac += __shfl_xor(sac, off, 64);
      if (ml == 0) {
        float ev = expf(-lrelu(sac));
        edge_e[e] = ev;
        atomicAdd(&a_rowsum[darr[i]], ev);
      }
    }
  }
}

// h_prime: one 32-lane group per dst node; coalesced 256B row-major P reads,
// w = rel_att * new_rank[src] computed inline, elu fused, float4 writes.
__global__ __launch_bounds__(256) void k_hprime(const bf16_t* __restrict__ P,
                                                const int* __restrict__ eid,
                                                const int* __restrict__ csr_start,
                                                const int* __restrict__ cnt,
                                                const float* __restrict__ rel_att,
                                                const int* __restrict__ sidx,
                                                const float* __restrict__ new_rank,
                                                float* __restrict__ out) {
  int g = (blockIdx.x << 3) | (threadIdx.x >> 5);
  if (g >= N_NODES) return;
  int m = threadIdx.x & 31;
  int start = csr_start[g], deg = cnt[g];
  float a0 = 0.f, a1 = 0.f, a2v = 0.f, a3v = 0.f;
  for (int i = 0; i < deg; ++i) {
    int e = eid[start + i];
    float we = rel_att[e] * new_rank[sidx[e]];
    bf16x4 p = *(const bf16x4*)(P + (size_t)e * 128 + m * 4);
    a0 += we * (float)p[0];
    a1 += we * (float)p[1];
    a2v += we * (float)p[2];
    a3v += we * (float)p[3];
  }
  float4 r;
  r.x = a0 > 0.f ? a0 : expm1f(a0);
  r.y = a1 > 0.f ? a1 : expm1f(a1);
  r.z = a2v > 0.f ? a2v : expm1f(a2v);
  r.w = a3v > 0.f ? a3v : expm1f(a3v);
  *(float4*)(out + (size_t)g * 128 + m * 4) = r;
}

// ---------- fallback (round-3) recompute-ACCUM pass ----------
template <bool ACCUM>
__global__ __launch_bounds__(256, 3) void k_pass(
    const float* __restrict__ eemb, const float* __restrict__ eembn,
    const bf16_t* __restrict__ uv, const int* __restrict__ sidx,
    const int* __restrict__ didx, const bf16_t* __restrict__ bp3,
    const float* __restrict__ a2, float* __restrict__ edge_e,
    float* __restrict__ a_rowsum, const float* __restrict__ rel_att,
    const float* __restrict__ new_rank, float* __restrict__ hout) {
  __shared__ bf16_t s_sum[128][136];
  const int tid = threadIdx.x;
  const long long e0 = (long long)blockIdx.x * 128;
  {
    const int g = tid >> 5;
    const int cl = (tid & 31) * 4;
#pragma unroll
    for (int i = 0; i < 16; ++i) {
      int el = i * 8 + g;
      long long e = e0 + el;
      float sx = 0.f, sy = 0.f, sz = 0.f, sw = 0.f;
      if (e < E_TOT) {
        int s = sidx[e], d = didx[e];
        bf16x4 u = *(const bf16x4*)(uv + (size_t)s * 256 + cl);
        bf16x4 v = *(const bf16x4*)(uv + (size_t)d * 256 + 128 + cl);
        sx = (float)u[0] + (float)v[0];
        sy = (float)u[1] + (float)v[1];
        sz = (float)u[2] + (float)v[2];
        sw = (float)u[3] + (float)v[3];
      }
      bf16x4 o = {(bf16_t)sx, (bf16_t)sy, (bf16_t)sz, (bf16_t)sw};
      *(bf16x4*)&s_sum[el][cl] = o;
    }
  }
  __syncthreads();

  const int lane = tid & 63;
  const int wv = tid >> 6;
  const long long e0w = e0 + wv * 32;
  if (e0w >= E_TOT) return;
  const int m = lane & 31, hi2 = lane >> 5;
  const long long e = e0w + m;
  const float* b2 = (e < E1N) ? (eemb + (size_t)e * 128)
                              : (eembn + (size_t)(e - E1N) * 128);
  const float* ar = b2 + hi2 * 8;

  const bf16x8* bp = (const bf16x8*)bp3;
  f32x16 acc[4];
#pragma unroll
  for (int nt = 0; nt < 4; ++nt)
#pragma unroll
    for (int r = 0; r < 16; ++r) acc[nt][r] = 0.f;

  auto loadA = [&](int ks) -> bf16x8 {
    float4 u0 = *(const float4*)(ar + ks * 16);
    float4 u1 = *(const float4*)(ar + ks * 16 + 4);
    bf16x8 rr = {(bf16_t)u0.x, (bf16_t)u0.y, (bf16_t)u0.z, (bf16_t)u0.w,
                 (bf16_t)u1.x, (bf16_t)u1.y, (bf16_t)u1.z, (bf16_t)u1.w};
    return rr;
  };

  bf16x8 a_cur = loadA(0);
  bf16x8 bb[4], bn[4];
#pragma unroll
  for (int nt = 0; nt < 4; ++nt) bb[nt] = bp[nt * 64 + lane];

#pragma unroll
  for (int ks = 0; ks < 8; ++ks) {
    bf16x8 a_nxt;
    if (ks < 7) {
      a_nxt = loadA(ks + 1);
#pragma unroll
      for (int nt = 0; nt < 4; ++nt) bn[nt] = bp[((ks + 1) * 4 + nt) * 64 + lane];
    }
#pragma unroll
    for (int nt = 0; nt < 4; ++nt)
      acc[nt] = __builtin_amdgcn_mfma_f32_32x32x16_bf16(a_cur, bb[nt], acc[nt], 0, 0, 0);
    a_cur = a_nxt;
#pragma unroll
    for (int nt = 0; nt < 4; ++nt) bb[nt] = bn[nt];
  }

  if (!ACCUM) {
    float sac[16];
#pragma unroll
    for (int r = 0; r < 16; ++r) sac[r] = 0.f;
#pragma unroll
    for (int nt = 0; nt < 4; ++nt) {
      float a2v = a2[nt * 32 + m];
      int o = nt * 32 + m;
#pragma unroll
      for (int r = 0; r < 16; ++r) {
        int row = (r & 3) + ((r >> 2) << 3) + (hi2 << 2);
        float c = acc[nt][r] + (float)s_sum[wv * 32 + row][o];
        sac[r] += lrelu(c) * a2v;
      }
    }
#pragma unroll
    for (int off = 1; off < 32; off <<= 1) {
#pragma unroll
      for (int r = 0; r < 16; ++r) sac[r] += __shfl_xor(sac[r], off, 64);
    }
    if (m == 0) {
#pragma unroll
      for (int r = 0; r < 16; ++r) {
        int row = (r & 3) + ((r >> 2) << 3) + (hi2 << 2);
        long long ee_i = e0w + row;
        float ev = expf(-lrelu(sac[r]));
        edge_e[ee_i] = ev;
        atomicAdd(&a_rowsum[didx[ee_i]], ev);
      }
    }
  } else {
    float w_m = rel_att[e] * new_rank[sidx[e]];
    int d = didx[e];
    float wr[16];
    int dr[16];
#pragma unroll
    for (int r = 0; r < 16; ++r) {
      int row = (r & 3) + ((r >> 2) << 3) + (hi2 << 2);
      wr[r] = __shfl(w_m, row, 64);
      dr[r] = __shfl(d, row, 64);
    }
#pragma unroll
    for (int nt = 0; nt < 4; ++nt) {
      int o = nt * 32 + m;
#pragma unroll
      for (int r = 0; r < 16; ++r) {
        int row = (r & 3) + ((r >> 2) << 3) + (hi2 << 2);
        float c = acc[nt][r] + (float)s_sum[wv * 32 + row][o];
        atomicAdd(&hout[(size_t)dr[r] * 128 + o], lrelu(c) * wr[r]);
      }
    }
  }
}

__global__ __launch_bounds__(256) void k_relatt(const float* __restrict__ edge_e,
                                                const int* __restrict__ didx,
                                                const int* __restrict__ sidx,
                                                const float* __restrict__ a_rowsum,
                                                float* __restrict__ rel_att,
                                                float* __restrict__ e_rowsum) {
  int e = blockIdx.x * 256 + threadIdx.x;
  if (e >= E_TOT) return;
  float rs = a_rowsum[didx[e]];
  rs = (rs == 0.f) ? EPSC : rs;
  float r = edge_e[e] / rs;
  rel_att[e] = r;
  atomicAdd(&e_rowsum[sidx[e]], r);
}

__global__ __launch_bounds__(256) void k_val(const float* __restrict__ rel_att,
                                             const int* __restrict__ sidx,
                                             const int* __restrict__ didx,
                                             const float* __restrict__ rank,
                                             const float* __restrict__ e_rowsum,
                                             float* __restrict__ e_colsum) {
  int e = blockIdx.x * 256 + threadIdx.x;
  if (e >= E_TOT) return;
  int s = sidx[e];
  float er = e_rowsum[s];
  er = (er == 0.f) ? EPSC : er;
  float val = rel_att[e] * rank[s] / er;
  atomicAdd(&e_colsum[didx[e]], val);
}

__global__ __launch_bounds__(256) void k_rank(const float* __restrict__ e_colsum,
                                              float* __restrict__ new_rank,
                                              float* __restrict__ out_tail) {
  int n = blockIdx.x * 256 + threadIdx.x;
  if (n >= N_NODES) return;
  float nr = 1.f - DAMP + DAMP * e_colsum[n];
  new_rank[n] = nr;
  out_tail[n] = nr;
}

__global__ __launch_bounds__(256) void k_elu(float* __restrict__ h) {
  int i = blockIdx.x * 256 + threadIdx.x;
  if (i < N_NODES * 128) {
    float x = h[i];
    h[i] = x > 0.f ? x : expm1f(x);
  }
}

extern "C" void kernel_launch(void* const* d_in, const int* in_sizes, int n_in,
                              void* d_out, int out_size, void* d_ws, size_t ws_size,
                              hipStream_t stream) {
  const float* input = (const float*)d_in[0];
  const int* edge = (const int*)d_in[1];
  const float* eemb = (const float*)d_in[2];
  const int* enh = (const int*)d_in[3];
  const float* eembn = (const float*)d_in[4];
  const float* rank = (const float*)d_in[5];
  const float* a = (const float*)d_in[6];
  const float* a2 = (const float*)d_in[7];
  float* out = (float*)d_out;

  int estride = (in_sizes[1] == 2 * E1N) ? 1 : 2;

  char* ws = (char*)d_ws;
  bf16_t* bp12 = (bf16_t*)(ws);                 //     65,536
  bf16_t* bp3 = (bf16_t*)(ws + 65536);          //     32,768 (32x32 order)
  bf16_t* bp3c = (bf16_t*)(ws + 98304);         //     32,768 (16x16 order)
  bf16_t* uv = (bf16_t*)(ws + 131072);          // 25,600,000
  int* sidx = (int*)(ws + 25731072);            //  2,000,000
  int* didx = (int*)(ws + 27731072);            //  2,000,000
  float* edge_e = (float*)(ws + 29731072);      //  2,000,000
  float* rel_att = (float*)(ws + 31731072);     //  2,000,000
  int* eid = (int*)(ws + 33731072);             //  2,000,000
  int* csr_start = (int*)(ws + 35731072);       //    200,000
  int* cursor = (int*)(ws + 35931072);          //    200,000
  int* cnt = (int*)(ws + 36131072);             //    200,000
  float* a_rowsum = (float*)(ws + 36331072);    //    200,000
  float* e_rowsum = (float*)(ws + 36531072);    //    200,000
  float* e_colsum = (float*)(ws + 36731072);    //    200,000
  float* new_rank = (float*)(ws + 36931072);    //    200,000
  bf16_t* P = (bf16_t*)(ws + 37131264);         // 128,000,000 (512B-aligned)
                                                // end: 165,131,264

  const bool big = ws_size >= 165131264ULL;

  const int NB = (E_TOT + 127) / 128;
  const int NB3 = (E_TOT + 63) / 64;
  const int EB = (E_TOT + 255) / 256;

  if (big) {
    // zero cnt + a_rowsum + e_rowsum + e_colsum (contiguous)
    hipMemsetAsync(cnt, 0, 4 * 200000, stream);

    k_pack12<<<128, 256, 0, stream>>>(a, bp12);
    k_pack3c<<<64, 256, 0, stream>>>(a, bp3c);
    k_edges<<<EB, 256, 0, stream>>>(edge, enh, sidx, didx, estride, cnt);
    k_scan<<<1, 256, 0, stream>>>(cnt, csr_start, cursor);
    k_pos<<<EB, 256, 0, stream>>>(didx, cursor, eid);
    k_uv<<<(N_NODES + 127) / 128, 256, 0, stream>>>(input, bp12, uv);

    k_passA3<<<NB3, 256, 0, stream>>>(eemb, eembn, uv, sidx, didx, bp3c, a2,
                                      edge_e, a_rowsum, P);
    k_relatt<<<EB, 256, 0, stream>>>(edge_e, didx, sidx, a_rowsum, rel_att, e_rowsum);
    k_val<<<EB, 256, 0, stream>>>(rel_att, sidx, didx, rank, e_rowsum, e_colsum);
    k_rank<<<(N_NODES + 255) / 256, 256, 0, stream>>>(e_colsum, new_rank,
                                                      out + (size_t)N_NODES * 128);
    k_hprime<<<(N_NODES + 7) / 8, 256, 0, stream>>>(P, eid, csr_start, cnt, rel_att,
                                                    sidx, new_rank, out);
  } else {
    // fallback: two-pass recompute + atomic hout
    hipMemsetAsync(cnt, 0, 4 * 200000, stream);
    hipMemsetAsync(out, 0, (size_t)N_NODES * 128 * 4, stream);

    k_pack12<<<128, 256, 0, stream>>>(a, bp12);
    k_pack3<<<64, 256, 0, stream>>>(a, bp3);
    k_edges<<<EB, 256, 0, stream>>>(edge, enh, sidx, didx, estride, nullptr);
    k_uv<<<(N_NODES + 127) / 128, 256, 0, stream>>>(input, bp12, uv);

    k_pass<false><<<NB, 256, 0, stream>>>(eemb, eembn, uv, sidx, didx, bp3, a2,
                                          edge_e, a_rowsum, nullptr, nullptr, nullptr);
    k_relatt<<<EB, 256, 0, stream>>>(edge_e, didx, sidx, a_rowsum, rel_att, e_rowsum);
    k_val<<<EB, 256, 0, stream>>>(rel_att, sidx, didx, rank, e_rowsum, e_colsum);
    k_rank<<<(N_NODES + 255) / 256, 256, 0, stream>>>(e_colsum, new_rank,
                                                      out + (size_t)N_NODES * 128);
    k_pass<true><<<NB, 256, 0, stream>>>(eemb, eembn, uv, sidx, didx, bp3, a2,
                                         nullptr, nullptr, rel_att, new_rank, out);
    k_elu<<<(N_NODES * 128 + 255) / 256, 256, 0, stream>>>(out);
  }
}